// Round 9
// baseline (506.112 us; speedup 1.0000x reference)
//
#include <hip/hip_runtime.h>

#define NODES_H 128
#define NB_K 16

typedef __attribute__((ext_vector_type(8))) short bf16x8;   // 8 bf16 (16B)
typedef __attribute__((ext_vector_type(8))) short h16x8;    // 8 fp16 (16B)
typedef __attribute__((ext_vector_type(4))) unsigned short u16x4; // 4 fp16 (8B)
typedef __attribute__((ext_vector_type(4))) float f32x4;

// fp32 -> bf16 round-to-nearest-even (no NaN inputs here)
__device__ __forceinline__ short f2bf(float f) {
    unsigned u = __float_as_uint(f);
    return (short)((u + 0x7fffu + ((u >> 16) & 1u)) >> 16);
}
__device__ __forceinline__ unsigned short f2h(float f) {
    _Float16 h = (_Float16)f;                    // v_cvt_f16_f32 (RTE)
    return __builtin_bit_cast(unsigned short, h);
}
__device__ __forceinline__ float h2f(unsigned short u) {
    return (float)__builtin_bit_cast(_Float16, u);
}
__device__ __forceinline__ bf16x8 pack8bf(float4 x, float4 y) {
    bf16x8 v;
    v[0] = f2bf(x.x); v[1] = f2bf(x.y); v[2] = f2bf(x.z); v[3] = f2bf(x.w);
    v[4] = f2bf(y.x); v[5] = f2bf(y.y); v[6] = f2bf(y.z); v[7] = f2bf(y.w);
    return v;
}
__device__ __forceinline__ h16x8 pack8h(float4 x, float4 y) {
    h16x8 v;
    v[0] = (short)f2h(x.x); v[1] = (short)f2h(x.y); v[2] = (short)f2h(x.z); v[3] = (short)f2h(x.w);
    v[4] = (short)f2h(y.x); v[5] = (short)f2h(y.y); v[6] = (short)f2h(y.z); v[7] = (short)f2h(y.w);
    return v;
}

// ws layout (full path):
//   [0, 400000)                scores (N floats)
//   [524288, 524288+32768)     packed Wa B-fragments (2048 x 16B)
//   [1048576, 1048576+25.6MB)  e16 (N x 128 fp16)
#define WS_B_OFF   524288
#define WS_E16_OFF 1048576

// ---------------------------------------------------------------------------
// Kernel 0: one-time pack of Wa into MFMA B-fragments (bf16), 2048 slots.
// slot s = jt*256 + kk*64 + l : 16 bf16 from Wa row jt*16+(l&15),
// cols kk*32 + (l>>4)*8 + [0..7]  (same (lane,elem)->k rule as the A pack;
// this rule PASSED on HW in round 4).
// ---------------------------------------------------------------------------
__global__ void pack_kernel(const float* __restrict__ Wa, void* __restrict__ wsB)
{
    int s = blockIdx.x * blockDim.x + threadIdx.x;
    if (s >= 2048) return;
    int jt = s >> 8, kk = (s >> 6) & 3, l = s & 63;
    const float* wrow = Wa + (size_t)(jt * 16 + (l & 15)) * NODES_H
                           + kk * 32 + ((l >> 4) * 8);
    float4 x = *(const float4*)wrow;
    float4 y = *(const float4*)(wrow + 4);
    ((bf16x8*)wsB)[s] = pack8bf(x, y);
}

// ---------------------------------------------------------------------------
// Kernel 1: per-node attention score via bf16 MFMA + e16 side-product.
//   score[n] = sum_j lrelu( (e[n,:] . Wa[j,:]) + b[j] ) * ua[j]
// One wave = 16 nodes. B-fragments staged from ws into LDS by plain vector
// copy (no conversion, no redundant Wa re-read per block). While holding
// each e-row chunk in registers, also store it as fp16 to e16 (gather-kernel
// input). D layout (HW-verified): col j = lane&15, node row = (lane>>4)*4
// + reg. Bias enters as the accumulator init.
// ---------------------------------------------------------------------------
__global__ __launch_bounds__(512) void score_kernel(
    const float* __restrict__ e, const void* __restrict__ wsB,
    const float* __restrict__ bias, const float* __restrict__ ua,
    float* __restrict__ scores, unsigned short* __restrict__ e16, int nNodes)
{
    __shared__ bf16x8 Bfrag[32][64];   // 32 KB

    const int t = threadIdx.x;
    // stage 2048 x 16B from ws (packed) into LDS — 4 slots/thread
    {
        const float4* src = (const float4*)wsB;
        float4* dst = (float4*)&Bfrag[0][0];
        #pragma unroll
        for (int q = 0; q < 4; ++q) dst[t + q * 512] = src[t + q * 512];
    }
    __syncthreads();

    const int lane = t & 63;
    const int g = blockIdx.x * (blockDim.x >> 6) + (t >> 6);   // group id
    const int nGroups = (nNodes + 15) >> 4;                    // 6250
    if (g >= nGroups) return;
    const int n0 = g << 4;

    // per-lane bias / ua for col j = jt*16 + (lane&15)
    float b_f[8], u_f[8];
    #pragma unroll
    for (int jt = 0; jt < 8; ++jt) {
        b_f[jt] = bias[jt * 16 + (lane & 15)];
        u_f[jt] = ua[jt * 16 + (lane & 15)];
    }

    // A fragments: node row n0+(lane&15), k = kk*32 + (lane>>4)*8 + [0..7]
    int arow = n0 + (lane & 15);
    if (arow >= nNodes) arow = nNodes - 1;   // no-op for N=100000
    const int coff = (lane >> 4) * 8;
    const float* ap = e + (size_t)arow * NODES_H + coff;
    unsigned short* hp = e16 + (size_t)arow * NODES_H + coff;
    bf16x8 a[4];
    #pragma unroll
    for (int kk = 0; kk < 4; ++kk) {
        float4 x = *(const float4*)(ap + kk * 32);
        float4 y = *(const float4*)(ap + kk * 32 + 4);
        a[kk] = pack8bf(x, y);
        *(h16x8*)(hp + kk * 32) = pack8h(x, y);   // e16 side product (16B store)
    }

    float sr[4] = {0.f, 0.f, 0.f, 0.f};
    #pragma unroll
    for (int jt = 0; jt < 8; ++jt) {
        f32x4 c = {b_f[jt], b_f[jt], b_f[jt], b_f[jt]};
        #pragma unroll
        for (int kk = 0; kk < 4; ++kk)
            c = __builtin_amdgcn_mfma_f32_16x16x32_bf16(a[kk], Bfrag[jt * 4 + kk][lane], c, 0, 0, 0);
        #pragma unroll
        for (int r = 0; r < 4; ++r) {
            float h = c[r];
            h = (h > 0.f) ? h : 0.1f * h;          // leaky_relu(0.1)
            sr[r] = fmaf(h, u_f[jt], sr[r]);
        }
    }

    // sum over 16 j-cols: butterfly within each 16-lane group
    #pragma unroll
    for (int off = 1; off < 16; off <<= 1) {
        #pragma unroll
        for (int r = 0; r < 4; ++r)
            sr[r] += __shfl_xor(sr[r], off, 64);
    }

    if ((lane & 15) == 0) {
        int nidx = n0 + ((lane >> 4) << 2);
        if (nidx + 3 < nNodes)
            *(float4*)(scores + nidx) = make_float4(sr[0], sr[1], sr[2], sr[3]);
        else
            for (int r = 0; r < 4 && nidx + r < nNodes; ++r)
                scores[nidx + r] = sr[r];
    }
}

// ---------------------------------------------------------------------------
// Kernel 2 (fp16 gather): softmax over K neighbor scores + aggregation.
// One wave per node. fp16 rows are 256B; lanes split 32/32 so one wave-load
// fetches TWO neighbor rows (8B/lane) -> 8 gather instructions per node,
// 410MB total gather traffic (vs 819MB fp32). Partials (even-k rows in half
// 0, odd-k in half 1) folded by shfl_xor(32). Residual e + agg stays fp32.
// ---------------------------------------------------------------------------
__global__ __launch_bounds__(256) void agg_kernel_h(
    const float* __restrict__ e, const unsigned short* __restrict__ e16,
    const int* __restrict__ nbrs, const float* __restrict__ scores,
    float* __restrict__ out, int nNodes)
{
    const int lane = threadIdx.x & 63;
    const int wave = (int)((blockIdx.x * blockDim.x + threadIdx.x) >> 6);
    if (wave >= nNodes) return;
    const int nu = __builtin_amdgcn_readfirstlane(wave);

    // neighbor indices: uniform -> scalar loads
    int idx[NB_K];
    #pragma unroll
    for (int k = 0; k < NB_K; ++k)
        idx[k] = __builtin_amdgcn_readfirstlane(nbrs[nu * NB_K + k]);

    const int half = lane >> 5;
    const int li = lane & 31;

    // issue all 8 row-pair gathers (depend only on idx, overlap the score loads)
    u16x4 gv[8];
    #pragma unroll
    for (int k8 = 0; k8 < 8; ++k8) {
        int ia = half ? idx[2 * k8 + 1] : idx[2 * k8];
        gv[k8] = *(const u16x4*)(e16 + (size_t)ia * NODES_H + li * 4);
    }

    // neighbor scores: uniform scattered scalar loads (400KB, cache-hot)
    float s[NB_K];
    #pragma unroll
    for (int k = 0; k < NB_K; ++k) s[k] = scores[idx[k]];

    // softmax over 16 (redundant per lane)
    float mx = s[0];
    #pragma unroll
    for (int k = 1; k < NB_K; ++k) mx = fmaxf(mx, s[k]);
    float sum = 0.f;
    #pragma unroll
    for (int k = 0; k < NB_K; ++k) { s[k] = __expf(s[k] - mx); sum += s[k]; }
    const float inv = 1.0f / sum;

    float o[4] = {0.f, 0.f, 0.f, 0.f};
    #pragma unroll
    for (int k8 = 0; k8 < 8; ++k8) {
        const float w = (half ? s[2 * k8 + 1] : s[2 * k8]) * inv;
        #pragma unroll
        for (int j = 0; j < 4; ++j)
            o[j] = fmaf(w, h2f((unsigned short)gv[k8][j]), o[j]);
    }
    // fold even-k half with odd-k half
    #pragma unroll
    for (int j = 0; j < 4; ++j) o[j] += __shfl_xor(o[j], 32, 64);

    if (lane < 32) {   // lanes 0..31 hold cols 4*li .. 4*li+3
        const float4 sf = *(const float4*)(e + (size_t)nu * NODES_H + li * 4);
        float4 r = make_float4(sf.x + o[0], sf.y + o[1], sf.z + o[2], sf.w + o[3]);
        *(float4*)(out + (size_t)nu * NODES_H + li * 4) = r;
    }
}

// ---------------------------------------------------------------------------
// Fallback kernels (round-4, verified passing) for small ws_size.
// ---------------------------------------------------------------------------
__global__ __launch_bounds__(256) void score_self_kernel(
    const float* __restrict__ e, const float* __restrict__ Wa,
    const float* __restrict__ bias, const float* __restrict__ ua,
    float* __restrict__ scores, int nNodes)
{
    __shared__ bf16x8 Bfrag[8][4][64];
    const int t = threadIdx.x;
    #pragma unroll
    for (int q = 0; q < 8; ++q) {
        int s = t * 8 + q;
        int jt = s >> 8, kk = (s >> 6) & 3, l = s & 63;
        const float* wrow = Wa + (size_t)(jt * 16 + (l & 15)) * NODES_H
                               + kk * 32 + ((l >> 4) * 8);
        float4 x = *(const float4*)wrow;
        float4 y = *(const float4*)(wrow + 4);
        Bfrag[jt][kk][l] = pack8bf(x, y);
    }
    __syncthreads();
    const int lane = t & 63;
    const int wave = blockIdx.x * (blockDim.x >> 6) + (t >> 6);
    const int nGroups = (nNodes + 15) >> 4;
    if (wave >= nGroups) return;
    const int n0 = wave << 4;
    float b_f[8], u_f[8];
    #pragma unroll
    for (int jt = 0; jt < 8; ++jt) {
        b_f[jt] = bias[jt * 16 + (lane & 15)];
        u_f[jt] = ua[jt * 16 + (lane & 15)];
    }
    int arow = n0 + (lane & 15);
    if (arow >= nNodes) arow = nNodes - 1;
    const float* ap = e + (size_t)arow * NODES_H + ((lane >> 4) * 8);
    bf16x8 a[4];
    #pragma unroll
    for (int kk = 0; kk < 4; ++kk) {
        float4 x = *(const float4*)(ap + kk * 32);
        float4 y = *(const float4*)(ap + kk * 32 + 4);
        a[kk] = pack8bf(x, y);
    }
    float sr[4] = {0.f, 0.f, 0.f, 0.f};
    #pragma unroll
    for (int jt = 0; jt < 8; ++jt) {
        f32x4 c = {b_f[jt], b_f[jt], b_f[jt], b_f[jt]};
        #pragma unroll
        for (int kk = 0; kk < 4; ++kk)
            c = __builtin_amdgcn_mfma_f32_16x16x32_bf16(a[kk], Bfrag[jt][kk][lane], c, 0, 0, 0);
        #pragma unroll
        for (int r = 0; r < 4; ++r) {
            float h = c[r];
            h = (h > 0.f) ? h : 0.1f * h;
            sr[r] = fmaf(h, u_f[jt], sr[r]);
        }
    }
    #pragma unroll
    for (int off = 1; off < 16; off <<= 1)
        #pragma unroll
        for (int r = 0; r < 4; ++r)
            sr[r] += __shfl_xor(sr[r], off, 64);
    if ((lane & 15) == 0) {
        int nidx = n0 + ((lane >> 4) << 2);
        if (nidx + 3 < nNodes)
            *(float4*)(scores + nidx) = make_float4(sr[0], sr[1], sr[2], sr[3]);
        else
            for (int r = 0; r < 4 && nidx + r < nNodes; ++r)
                scores[nidx + r] = sr[r];
    }
}

__global__ __launch_bounds__(256) void agg_kernel_f32(
    const float* __restrict__ e, const int* __restrict__ nbrs,
    const float* __restrict__ scores, float* __restrict__ out, int nNodes)
{
    const int lane = threadIdx.x & 63;
    const int wave = (int)((blockIdx.x * blockDim.x + threadIdx.x) >> 6);
    if (wave >= nNodes) return;
    const int nu = __builtin_amdgcn_readfirstlane(wave);
    int idx[NB_K];
    #pragma unroll
    for (int k = 0; k < NB_K; ++k)
        idx[k] = __builtin_amdgcn_readfirstlane(nbrs[nu * NB_K + k]);
    float s[NB_K];
    #pragma unroll
    for (int k = 0; k < NB_K; ++k) s[k] = scores[idx[k]];
    float mx = s[0];
    #pragma unroll
    for (int k = 1; k < NB_K; ++k) mx = fmaxf(mx, s[k]);
    float sum = 0.f;
    #pragma unroll
    for (int k = 0; k < NB_K; ++k) { s[k] = __expf(s[k] - mx); sum += s[k]; }
    const float inv = 1.0f / sum;
    const float2* e2 = (const float2*)e;
    const size_t base2 = (size_t)nu * (NODES_H / 2) + lane;
    float2 self = e2[base2];
    float2 g[NB_K];
    #pragma unroll
    for (int k = 0; k < NB_K; ++k)
        g[k] = e2[(size_t)idx[k] * (NODES_H / 2) + lane];
    float o0 = self.x, o1 = self.y;
    #pragma unroll
    for (int k = 0; k < NB_K; ++k) {
        const float w = s[k] * inv;
        o0 = fmaf(w, g[k].x, o0);
        o1 = fmaf(w, g[k].y, o1);
    }
    ((float2*)out)[base2] = make_float2(o0, o1);
}

// ---------------------------------------------------------------------------
extern "C" void kernel_launch(void* const* d_in, const int* in_sizes, int n_in,
                              void* d_out, int out_size, void* d_ws, size_t ws_size,
                              hipStream_t stream) {
    const float* e   = (const float*)d_in[0];
    const float* Wa  = (const float*)d_in[1];
    const float* Wb  = (const float*)d_in[2];
    const float* ua  = (const float*)d_in[3];
    const int*   nb  = (const int*)d_in[4];
    float* out = (float*)d_out;

    const int nNodes = in_sizes[0] / NODES_H;   // 100000
    float* scores = (float*)d_ws;

    const size_t need = (size_t)WS_E16_OFF + (size_t)nNodes * NODES_H * 2;
    if (ws_size >= need) {
        void* wsB = (void*)((char*)d_ws + WS_B_OFF);
        unsigned short* e16 = (unsigned short*)((char*)d_ws + WS_E16_OFF);

        pack_kernel<<<8, 256, 0, stream>>>(Wa, wsB);

        const int nGroups = (nNodes + 15) / 16;            // 6250
        const int blocks1 = (nGroups + 7) / 8;             // 782 (8 waves/blk)
        score_kernel<<<blocks1, 512, 0, stream>>>(e, wsB, Wb, ua, scores, e16, nNodes);

        const int blocks2 = (nNodes + 3) / 4;              // one wave per node
        agg_kernel_h<<<blocks2, 256, 0, stream>>>(e, e16, nb, scores, out, nNodes);
    } else {
        const int nGroups = (nNodes + 15) / 16;
        const int blocks1 = (nGroups + 3) / 4;
        score_self_kernel<<<blocks1, 256, 0, stream>>>(e, Wa, Wb, ua, scores, nNodes);
        const int blocks2 = (nNodes + 3) / 4;
        agg_kernel_f32<<<blocks2, 256, 0, stream>>>(e, nb, scores, out, nNodes);
    }
}

// Round 10
// 177.486 us; speedup vs baseline: 2.8516x; 2.8516x over previous
//
#include <hip/hip_runtime.h>

#define NODES_H 128
#define NB_K 16

typedef __attribute__((ext_vector_type(8))) short bf16x8;   // 8 bf16 (16B)
typedef __attribute__((ext_vector_type(8))) short h16x8;    // 8 fp16 (16B)
typedef __attribute__((ext_vector_type(4))) float f32x4;

// fp32 -> bf16 round-to-nearest-even (no NaN inputs here)
__device__ __forceinline__ short f2bf(float f) {
    unsigned u = __float_as_uint(f);
    return (short)((u + 0x7fffu + ((u >> 16) & 1u)) >> 16);
}
__device__ __forceinline__ unsigned short f2h(float f) {
    _Float16 h = (_Float16)f;                    // v_cvt_f16_f32 (RTE)
    return __builtin_bit_cast(unsigned short, h);
}
__device__ __forceinline__ float h2f(unsigned short u) {
    return (float)__builtin_bit_cast(_Float16, u);
}
__device__ __forceinline__ bf16x8 pack8bf(float4 x, float4 y) {
    bf16x8 v;
    v[0] = f2bf(x.x); v[1] = f2bf(x.y); v[2] = f2bf(x.z); v[3] = f2bf(x.w);
    v[4] = f2bf(y.x); v[5] = f2bf(y.y); v[6] = f2bf(y.z); v[7] = f2bf(y.w);
    return v;
}
__device__ __forceinline__ h16x8 pack8h(float4 x, float4 y) {
    h16x8 v;
    v[0] = (short)f2h(x.x); v[1] = (short)f2h(x.y); v[2] = (short)f2h(x.z); v[3] = (short)f2h(x.w);
    v[4] = (short)f2h(y.x); v[5] = (short)f2h(y.y); v[6] = (short)f2h(y.z); v[7] = (short)f2h(y.w);
    return v;
}

// ws layout (full path):
//   [0, 400000)                scores (N floats)
//   [524288, 524288+32768)     packed Wa B-fragments (2048 x 16B)
//   [1048576, 1048576+25.6MB)  e16 (N x 128 fp16)
#define WS_B_OFF   524288
#define WS_E16_OFF 1048576

// ---------------------------------------------------------------------------
// Kernel 0: one-time pack of Wa into MFMA B-fragments (bf16), 2048 slots.
// (ran and passed in round 9 — unchanged)
// ---------------------------------------------------------------------------
__global__ void pack_kernel(const float* __restrict__ Wa, void* __restrict__ wsB)
{
    int s = blockIdx.x * blockDim.x + threadIdx.x;
    if (s >= 2048) return;
    int jt = s >> 8, kk = (s >> 6) & 3, l = s & 63;
    const float* wrow = Wa + (size_t)(jt * 16 + (l & 15)) * NODES_H
                           + kk * 32 + ((l >> 4) * 8);
    float4 x = *(const float4*)wrow;
    float4 y = *(const float4*)(wrow + 4);
    ((bf16x8*)wsB)[s] = pack8bf(x, y);
}

// ---------------------------------------------------------------------------
// Kernel 1: per-node attention score via bf16 MFMA + e16 side-product.
// (ran and passed in round 9 — unchanged; will profile this round)
// ---------------------------------------------------------------------------
__global__ __launch_bounds__(512) void score_kernel(
    const float* __restrict__ e, const void* __restrict__ wsB,
    const float* __restrict__ bias, const float* __restrict__ ua,
    float* __restrict__ scores, unsigned short* __restrict__ e16, int nNodes)
{
    __shared__ bf16x8 Bfrag[32][64];   // 32 KB

    const int t = threadIdx.x;
    {
        const float4* src = (const float4*)wsB;
        float4* dst = (float4*)&Bfrag[0][0];
        #pragma unroll
        for (int q = 0; q < 4; ++q) dst[t + q * 512] = src[t + q * 512];
    }
    __syncthreads();

    const int lane = t & 63;
    const int g = blockIdx.x * (blockDim.x >> 6) + (t >> 6);   // group id
    const int nGroups = (nNodes + 15) >> 4;                    // 6250
    if (g >= nGroups) return;
    const int n0 = g << 4;

    float b_f[8], u_f[8];
    #pragma unroll
    for (int jt = 0; jt < 8; ++jt) {
        b_f[jt] = bias[jt * 16 + (lane & 15)];
        u_f[jt] = ua[jt * 16 + (lane & 15)];
    }

    int arow = n0 + (lane & 15);
    if (arow >= nNodes) arow = nNodes - 1;   // no-op for N=100000
    const int coff = (lane >> 4) * 8;
    const float* ap = e + (size_t)arow * NODES_H + coff;
    unsigned short* hp = e16 + (size_t)arow * NODES_H + coff;
    bf16x8 a[4];
    #pragma unroll
    for (int kk = 0; kk < 4; ++kk) {
        float4 x = *(const float4*)(ap + kk * 32);
        float4 y = *(const float4*)(ap + kk * 32 + 4);
        a[kk] = pack8bf(x, y);
        *(h16x8*)(hp + kk * 32) = pack8h(x, y);   // e16 side product
    }

    float sr[4] = {0.f, 0.f, 0.f, 0.f};
    #pragma unroll
    for (int jt = 0; jt < 8; ++jt) {
        f32x4 c = {b_f[jt], b_f[jt], b_f[jt], b_f[jt]};
        #pragma unroll
        for (int kk = 0; kk < 4; ++kk)
            c = __builtin_amdgcn_mfma_f32_16x16x32_bf16(a[kk], Bfrag[jt * 4 + kk][lane], c, 0, 0, 0);
        #pragma unroll
        for (int r = 0; r < 4; ++r) {
            float h = c[r];
            h = (h > 0.f) ? h : 0.1f * h;          // leaky_relu(0.1)
            sr[r] = fmaf(h, u_f[jt], sr[r]);
        }
    }

    #pragma unroll
    for (int off = 1; off < 16; off <<= 1) {
        #pragma unroll
        for (int r = 0; r < 4; ++r)
            sr[r] += __shfl_xor(sr[r], off, 64);
    }

    if ((lane & 15) == 0) {
        int nidx = n0 + ((lane >> 4) << 2);
        if (nidx + 3 < nNodes)
            *(float4*)(scores + nidx) = make_float4(sr[0], sr[1], sr[2], sr[3]);
        else
            for (int r = 0; r < 4 && nidx + r < nNodes; ++r)
                scores[nidx + r] = sr[r];
    }
}

// ---------------------------------------------------------------------------
// Kernel 2 (fp16 gather, round-4 code shape): softmax + aggregation.
// EXACT structural copy of the HW-verified agg_kernel_f32 (VGPR=32, LDS=0,
// 125us): one wave per node, one row per wave-load, lane l owns cols
// {2l, 2l+1}. Only change: the 16 row gathers load ONE uint (2 fp16, 4B)
// per lane from e16 instead of float2 (8B) from e — halves gather bytes.
// No lane-half split, no shuffles (those triggered promote-alloca/spill in
// round 9: LDS_Block=16K, 3.4e7 bank conflicts, WRITE 425MB).
// ---------------------------------------------------------------------------
__global__ __launch_bounds__(256) void agg_kernel_h2(
    const float* __restrict__ e, const unsigned short* __restrict__ e16,
    const int* __restrict__ nbrs, const float* __restrict__ scores,
    float* __restrict__ out, int nNodes)
{
    const int lane = threadIdx.x & 63;
    const int wave = (int)((blockIdx.x * blockDim.x + threadIdx.x) >> 6);
    if (wave >= nNodes) return;
    const int nu = __builtin_amdgcn_readfirstlane(wave);

    int idx[NB_K];
    #pragma unroll
    for (int k = 0; k < NB_K; ++k)
        idx[k] = __builtin_amdgcn_readfirstlane(nbrs[nu * NB_K + k]);

    float s[NB_K];
    #pragma unroll
    for (int k = 0; k < NB_K; ++k) s[k] = scores[idx[k]];

    float mx = s[0];
    #pragma unroll
    for (int k = 1; k < NB_K; ++k) mx = fmaxf(mx, s[k]);
    float sum = 0.f;
    #pragma unroll
    for (int k = 0; k < NB_K; ++k) { s[k] = __expf(s[k] - mx); sum += s[k]; }
    const float inv = 1.0f / sum;

    const float2* e2 = (const float2*)e;
    const size_t base2 = (size_t)nu * (NODES_H / 2) + lane;
    float2 self = e2[base2];

    // 16 coalesced row gathers: one dword (2 fp16) per lane = 256B per row
    const unsigned* e16d = (const unsigned*)e16;
    unsigned g[NB_K];
    #pragma unroll
    for (int k = 0; k < NB_K; ++k)
        g[k] = e16d[(size_t)idx[k] * (NODES_H / 2) + lane];

    float o0 = self.x, o1 = self.y;
    #pragma unroll
    for (int k = 0; k < NB_K; ++k) {
        const float w = s[k] * inv;
        o0 = fmaf(w, h2f((unsigned short)(g[k] & 0xffffu)), o0);
        o1 = fmaf(w, h2f((unsigned short)(g[k] >> 16)), o1);
    }

    ((float2*)out)[base2] = make_float2(o0, o1);
}

// ---------------------------------------------------------------------------
// Fallback kernels (round-4, verified passing) for small ws_size.
// ---------------------------------------------------------------------------
__global__ __launch_bounds__(256) void score_self_kernel(
    const float* __restrict__ e, const float* __restrict__ Wa,
    const float* __restrict__ bias, const float* __restrict__ ua,
    float* __restrict__ scores, int nNodes)
{
    __shared__ bf16x8 Bfrag[8][4][64];
    const int t = threadIdx.x;
    #pragma unroll
    for (int q = 0; q < 8; ++q) {
        int s = t * 8 + q;
        int jt = s >> 8, kk = (s >> 6) & 3, l = s & 63;
        const float* wrow = Wa + (size_t)(jt * 16 + (l & 15)) * NODES_H
                               + kk * 32 + ((l >> 4) * 8);
        float4 x = *(const float4*)wrow;
        float4 y = *(const float4*)(wrow + 4);
        Bfrag[jt][kk][l] = pack8bf(x, y);
    }
    __syncthreads();
    const int lane = t & 63;
    const int wave = blockIdx.x * (blockDim.x >> 6) + (t >> 6);
    const int nGroups = (nNodes + 15) >> 4;
    if (wave >= nGroups) return;
    const int n0 = wave << 4;
    float b_f[8], u_f[8];
    #pragma unroll
    for (int jt = 0; jt < 8; ++jt) {
        b_f[jt] = bias[jt * 16 + (lane & 15)];
        u_f[jt] = ua[jt * 16 + (lane & 15)];
    }
    int arow = n0 + (lane & 15);
    if (arow >= nNodes) arow = nNodes - 1;
    const float* ap = e + (size_t)arow * NODES_H + ((lane >> 4) * 8);
    bf16x8 a[4];
    #pragma unroll
    for (int kk = 0; kk < 4; ++kk) {
        float4 x = *(const float4*)(ap + kk * 32);
        float4 y = *(const float4*)(ap + kk * 32 + 4);
        a[kk] = pack8bf(x, y);
    }
    float sr[4] = {0.f, 0.f, 0.f, 0.f};
    #pragma unroll
    for (int jt = 0; jt < 8; ++jt) {
        f32x4 c = {b_f[jt], b_f[jt], b_f[jt], b_f[jt]};
        #pragma unroll
        for (int kk = 0; kk < 4; ++kk)
            c = __builtin_amdgcn_mfma_f32_16x16x32_bf16(a[kk], Bfrag[jt][kk][lane], c, 0, 0, 0);
        #pragma unroll
        for (int r = 0; r < 4; ++r) {
            float h = c[r];
            h = (h > 0.f) ? h : 0.1f * h;
            sr[r] = fmaf(h, u_f[jt], sr[r]);
        }
    }
    #pragma unroll
    for (int off = 1; off < 16; off <<= 1)
        #pragma unroll
        for (int r = 0; r < 4; ++r)
            sr[r] += __shfl_xor(sr[r], off, 64);
    if ((lane & 15) == 0) {
        int nidx = n0 + ((lane >> 4) << 2);
        if (nidx + 3 < nNodes)
            *(float4*)(scores + nidx) = make_float4(sr[0], sr[1], sr[2], sr[3]);
        else
            for (int r = 0; r < 4 && nidx + r < nNodes; ++r)
                scores[nidx + r] = sr[r];
    }
}

__global__ __launch_bounds__(256) void agg_kernel_f32(
    const float* __restrict__ e, const int* __restrict__ nbrs,
    const float* __restrict__ scores, float* __restrict__ out, int nNodes)
{
    const int lane = threadIdx.x & 63;
    const int wave = (int)((blockIdx.x * blockDim.x + threadIdx.x) >> 6);
    if (wave >= nNodes) return;
    const int nu = __builtin_amdgcn_readfirstlane(wave);
    int idx[NB_K];
    #pragma unroll
    for (int k = 0; k < NB_K; ++k)
        idx[k] = __builtin_amdgcn_readfirstlane(nbrs[nu * NB_K + k]);
    float s[NB_K];
    #pragma unroll
    for (int k = 0; k < NB_K; ++k) s[k] = scores[idx[k]];
    float mx = s[0];
    #pragma unroll
    for (int k = 1; k < NB_K; ++k) mx = fmaxf(mx, s[k]);
    float sum = 0.f;
    #pragma unroll
    for (int k = 0; k < NB_K; ++k) { s[k] = __expf(s[k] - mx); sum += s[k]; }
    const float inv = 1.0f / sum;
    const float2* e2 = (const float2*)e;
    const size_t base2 = (size_t)nu * (NODES_H / 2) + lane;
    float2 self = e2[base2];
    float2 g[NB_K];
    #pragma unroll
    for (int k = 0; k < NB_K; ++k)
        g[k] = e2[(size_t)idx[k] * (NODES_H / 2) + lane];
    float o0 = self.x, o1 = self.y;
    #pragma unroll
    for (int k = 0; k < NB_K; ++k) {
        const float w = s[k] * inv;
        o0 = fmaf(w, g[k].x, o0);
        o1 = fmaf(w, g[k].y, o1);
    }
    ((float2*)out)[base2] = make_float2(o0, o1);
}

// ---------------------------------------------------------------------------
extern "C" void kernel_launch(void* const* d_in, const int* in_sizes, int n_in,
                              void* d_out, int out_size, void* d_ws, size_t ws_size,
                              hipStream_t stream) {
    const float* e   = (const float*)d_in[0];
    const float* Wa  = (const float*)d_in[1];
    const float* Wb  = (const float*)d_in[2];
    const float* ua  = (const float*)d_in[3];
    const int*   nb  = (const int*)d_in[4];
    float* out = (float*)d_out;

    const int nNodes = in_sizes[0] / NODES_H;   // 100000
    float* scores = (float*)d_ws;

    const size_t need = (size_t)WS_E16_OFF + (size_t)nNodes * NODES_H * 2;
    if (ws_size >= need) {
        void* wsB = (void*)((char*)d_ws + WS_B_OFF);
        unsigned short* e16 = (unsigned short*)((char*)d_ws + WS_E16_OFF);

        pack_kernel<<<8, 256, 0, stream>>>(Wa, wsB);

        const int nGroups = (nNodes + 15) / 16;            // 6250
        const int blocks1 = (nGroups + 7) / 8;             // 782 (8 waves/blk)
        score_kernel<<<blocks1, 512, 0, stream>>>(e, wsB, Wb, ua, scores, e16, nNodes);

        const int blocks2 = (nNodes + 3) / 4;              // one wave per node
        agg_kernel_h2<<<blocks2, 256, 0, stream>>>(e, e16, nb, scores, out, nNodes);
    } else {
        const int nGroups = (nNodes + 15) / 16;
        const int blocks1 = (nGroups + 3) / 4;
        score_self_kernel<<<blocks1, 256, 0, stream>>>(e, Wa, Wb, ua, scores, nNodes);
        const int blocks2 = (nNodes + 3) / 4;
        agg_kernel_f32<<<blocks2, 256, 0, stream>>>(e, nb, scores, out, nNodes);
    }
}

// Round 11
// 174.451 us; speedup vs baseline: 2.9012x; 1.0174x over previous
//
#include <hip/hip_runtime.h>

#define NODES_H 128
#define NB_K 16

typedef __attribute__((ext_vector_type(8))) short bf16x8;   // 8 bf16 (16B)
typedef __attribute__((ext_vector_type(8))) short h16x8;    // 8 fp16 (16B)
typedef __attribute__((ext_vector_type(4))) float f32x4;

// fp32 -> bf16 round-to-nearest-even (no NaN inputs here)
__device__ __forceinline__ short f2bf(float f) {
    unsigned u = __float_as_uint(f);
    return (short)((u + 0x7fffu + ((u >> 16) & 1u)) >> 16);
}
__device__ __forceinline__ unsigned short f2h(float f) {
    _Float16 h = (_Float16)f;                    // v_cvt_f16_f32 (RTE)
    return __builtin_bit_cast(unsigned short, h);
}
__device__ __forceinline__ float h2f(unsigned short u) {
    return (float)__builtin_bit_cast(_Float16, u);
}
__device__ __forceinline__ bf16x8 pack8bf(float4 x, float4 y) {
    bf16x8 v;
    v[0] = f2bf(x.x); v[1] = f2bf(x.y); v[2] = f2bf(x.z); v[3] = f2bf(x.w);
    v[4] = f2bf(y.x); v[5] = f2bf(y.y); v[6] = f2bf(y.z); v[7] = f2bf(y.w);
    return v;
}
__device__ __forceinline__ h16x8 pack8h(float4 x, float4 y) {
    h16x8 v;
    v[0] = (short)f2h(x.x); v[1] = (short)f2h(x.y); v[2] = (short)f2h(x.z); v[3] = (short)f2h(x.w);
    v[4] = (short)f2h(y.x); v[5] = (short)f2h(y.y); v[6] = (short)f2h(y.z); v[7] = (short)f2h(y.w);
    return v;
}

// ws layout (full path):
//   [0, 400000)                scores (N floats)
//   [524288, 524288+32768)     packed Wa B-fragments (2048 x 16B)
//   [1048576, 1048576+25.6MB)  e16 (N x 128 fp16)
#define WS_B_OFF   524288
#define WS_E16_OFF 1048576

// ---------------------------------------------------------------------------
// Kernel 0: one-time pack of Wa into MFMA B-fragments (bf16), 2048 slots.
// (HW-verified rounds 9/10 — unchanged)
// ---------------------------------------------------------------------------
__global__ void pack_kernel(const float* __restrict__ Wa, void* __restrict__ wsB)
{
    int s = blockIdx.x * blockDim.x + threadIdx.x;
    if (s >= 2048) return;
    int jt = s >> 8, kk = (s >> 6) & 3, l = s & 63;
    const float* wrow = Wa + (size_t)(jt * 16 + (l & 15)) * NODES_H
                           + kk * 32 + ((l >> 4) * 8);
    float4 x = *(const float4*)wrow;
    float4 y = *(const float4*)(wrow + 4);
    ((bf16x8*)wsB)[s] = pack8bf(x, y);
}

// ---------------------------------------------------------------------------
// Kernel 1: per-node attention score via bf16 MFMA + e16 side-product.
// (HW-verified rounds 9/10 — unchanged; should surface in top-5 this round
// now that agg drops below it -> first counters for this kernel)
// ---------------------------------------------------------------------------
__global__ __launch_bounds__(512) void score_kernel(
    const float* __restrict__ e, const void* __restrict__ wsB,
    const float* __restrict__ bias, const float* __restrict__ ua,
    float* __restrict__ scores, unsigned short* __restrict__ e16, int nNodes)
{
    __shared__ bf16x8 Bfrag[32][64];   // 32 KB

    const int t = threadIdx.x;
    {
        const float4* src = (const float4*)wsB;
        float4* dst = (float4*)&Bfrag[0][0];
        #pragma unroll
        for (int q = 0; q < 4; ++q) dst[t + q * 512] = src[t + q * 512];
    }
    __syncthreads();

    const int lane = t & 63;
    const int g = blockIdx.x * (blockDim.x >> 6) + (t >> 6);   // group id
    const int nGroups = (nNodes + 15) >> 4;                    // 6250
    if (g >= nGroups) return;
    const int n0 = g << 4;

    float b_f[8], u_f[8];
    #pragma unroll
    for (int jt = 0; jt < 8; ++jt) {
        b_f[jt] = bias[jt * 16 + (lane & 15)];
        u_f[jt] = ua[jt * 16 + (lane & 15)];
    }

    int arow = n0 + (lane & 15);
    if (arow >= nNodes) arow = nNodes - 1;   // no-op for N=100000
    const int coff = (lane >> 4) * 8;
    const float* ap = e + (size_t)arow * NODES_H + coff;
    unsigned short* hp = e16 + (size_t)arow * NODES_H + coff;
    bf16x8 a[4];
    #pragma unroll
    for (int kk = 0; kk < 4; ++kk) {
        float4 x = *(const float4*)(ap + kk * 32);
        float4 y = *(const float4*)(ap + kk * 32 + 4);
        a[kk] = pack8bf(x, y);
        *(h16x8*)(hp + kk * 32) = pack8h(x, y);   // e16 side product
    }

    float sr[4] = {0.f, 0.f, 0.f, 0.f};
    #pragma unroll
    for (int jt = 0; jt < 8; ++jt) {
        f32x4 c = {b_f[jt], b_f[jt], b_f[jt], b_f[jt]};
        #pragma unroll
        for (int kk = 0; kk < 4; ++kk)
            c = __builtin_amdgcn_mfma_f32_16x16x32_bf16(a[kk], Bfrag[jt * 4 + kk][lane], c, 0, 0, 0);
        #pragma unroll
        for (int r = 0; r < 4; ++r) {
            float h = c[r];
            h = (h > 0.f) ? h : 0.1f * h;          // leaky_relu(0.1)
            sr[r] = fmaf(h, u_f[jt], sr[r]);
        }
    }

    #pragma unroll
    for (int off = 1; off < 16; off <<= 1) {
        #pragma unroll
        for (int r = 0; r < 4; ++r)
            sr[r] += __shfl_xor(sr[r], off, 64);
    }

    if ((lane & 15) == 0) {
        int nidx = n0 + ((lane >> 4) << 2);
        if (nidx + 3 < nNodes)
            *(float4*)(scores + nidx) = make_float4(sr[0], sr[1], sr[2], sr[3]);
        else
            for (int r = 0; r < 4 && nidx + r < nNodes; ++r)
                scores[nidx + r] = sr[r];
    }
}

// ---------------------------------------------------------------------------
// Kernel 2 (fp16 gather, all-e16): softmax + aggregation.
// Same HW-verified shape as round-10's agg_kernel_h2 (VGPR=24, LDS=0,
// 68.5us), with ONE change: the self row also comes from e16 (one dword
// per lane) -> the 51MB fp32 e stream is gone entirely. FETCH 217->~166MB.
// Added error <= |e|*2^-11 ~ 2.7e-3 on the residual term.
// ---------------------------------------------------------------------------
__global__ __launch_bounds__(256) void agg_kernel_h3(
    const unsigned short* __restrict__ e16,
    const int* __restrict__ nbrs, const float* __restrict__ scores,
    float* __restrict__ out, int nNodes)
{
    const int lane = threadIdx.x & 63;
    const int wave = (int)((blockIdx.x * blockDim.x + threadIdx.x) >> 6);
    if (wave >= nNodes) return;
    const int nu = __builtin_amdgcn_readfirstlane(wave);

    int idx[NB_K];
    #pragma unroll
    for (int k = 0; k < NB_K; ++k)
        idx[k] = __builtin_amdgcn_readfirstlane(nbrs[nu * NB_K + k]);

    float s[NB_K];
    #pragma unroll
    for (int k = 0; k < NB_K; ++k) s[k] = scores[idx[k]];

    float mx = s[0];
    #pragma unroll
    for (int k = 1; k < NB_K; ++k) mx = fmaxf(mx, s[k]);
    float sum = 0.f;
    #pragma unroll
    for (int k = 0; k < NB_K; ++k) { s[k] = __expf(s[k] - mx); sum += s[k]; }
    const float inv = 1.0f / sum;

    const unsigned* e16d = (const unsigned*)e16;
    const size_t base2 = (size_t)nu * (NODES_H / 2) + lane;

    // self row: one dword (2 fp16) per lane
    unsigned selfd = e16d[base2];

    // 16 coalesced row gathers: one dword (2 fp16) per lane = 256B per row
    unsigned g[NB_K];
    #pragma unroll
    for (int k = 0; k < NB_K; ++k)
        g[k] = e16d[(size_t)idx[k] * (NODES_H / 2) + lane];

    float o0 = h2f((unsigned short)(selfd & 0xffffu));
    float o1 = h2f((unsigned short)(selfd >> 16));
    #pragma unroll
    for (int k = 0; k < NB_K; ++k) {
        const float w = s[k] * inv;
        o0 = fmaf(w, h2f((unsigned short)(g[k] & 0xffffu)), o0);
        o1 = fmaf(w, h2f((unsigned short)(g[k] >> 16)), o1);
    }

    ((float2*)out)[base2] = make_float2(o0, o1);
}

// ---------------------------------------------------------------------------
// Fallback kernels (round-4, verified passing) for small ws_size.
// ---------------------------------------------------------------------------
__global__ __launch_bounds__(256) void score_self_kernel(
    const float* __restrict__ e, const float* __restrict__ Wa,
    const float* __restrict__ bias, const float* __restrict__ ua,
    float* __restrict__ scores, int nNodes)
{
    __shared__ bf16x8 Bfrag[8][4][64];
    const int t = threadIdx.x;
    #pragma unroll
    for (int q = 0; q < 8; ++q) {
        int s = t * 8 + q;
        int jt = s >> 8, kk = (s >> 6) & 3, l = s & 63;
        const float* wrow = Wa + (size_t)(jt * 16 + (l & 15)) * NODES_H
                               + kk * 32 + ((l >> 4) * 8);
        float4 x = *(const float4*)wrow;
        float4 y = *(const float4*)(wrow + 4);
        Bfrag[jt][kk][l] = pack8bf(x, y);
    }
    __syncthreads();
    const int lane = t & 63;
    const int wave = blockIdx.x * (blockDim.x >> 6) + (t >> 6);
    const int nGroups = (nNodes + 15) >> 4;
    if (wave >= nGroups) return;
    const int n0 = wave << 4;
    float b_f[8], u_f[8];
    #pragma unroll
    for (int jt = 0; jt < 8; ++jt) {
        b_f[jt] = bias[jt * 16 + (lane & 15)];
        u_f[jt] = ua[jt * 16 + (lane & 15)];
    }
    int arow = n0 + (lane & 15);
    if (arow >= nNodes) arow = nNodes - 1;
    const float* ap = e + (size_t)arow * NODES_H + ((lane >> 4) * 8);
    bf16x8 a[4];
    #pragma unroll
    for (int kk = 0; kk < 4; ++kk) {
        float4 x = *(const float4*)(ap + kk * 32);
        float4 y = *(const float4*)(ap + kk * 32 + 4);
        a[kk] = pack8bf(x, y);
    }
    float sr[4] = {0.f, 0.f, 0.f, 0.f};
    #pragma unroll
    for (int jt = 0; jt < 8; ++jt) {
        f32x4 c = {b_f[jt], b_f[jt], b_f[jt], b_f[jt]};
        #pragma unroll
        for (int kk = 0; kk < 4; ++kk)
            c = __builtin_amdgcn_mfma_f32_16x16x32_bf16(a[kk], Bfrag[jt][kk][lane], c, 0, 0, 0);
        #pragma unroll
        for (int r = 0; r < 4; ++r) {
            float h = c[r];
            h = (h > 0.f) ? h : 0.1f * h;
            sr[r] = fmaf(h, u_f[jt], sr[r]);
        }
    }
    #pragma unroll
    for (int off = 1; off < 16; off <<= 1)
        #pragma unroll
        for (int r = 0; r < 4; ++r)
            sr[r] += __shfl_xor(sr[r], off, 64);
    if ((lane & 15) == 0) {
        int nidx = n0 + ((lane >> 4) << 2);
        if (nidx + 3 < nNodes)
            *(float4*)(scores + nidx) = make_float4(sr[0], sr[1], sr[2], sr[3]);
        else
            for (int r = 0; r < 4 && nidx + r < nNodes; ++r)
                scores[nidx + r] = sr[r];
    }
}

__global__ __launch_bounds__(256) void agg_kernel_f32(
    const float* __restrict__ e, const int* __restrict__ nbrs,
    const float* __restrict__ scores, float* __restrict__ out, int nNodes)
{
    const int lane = threadIdx.x & 63;
    const int wave = (int)((blockIdx.x * blockDim.x + threadIdx.x) >> 6);
    if (wave >= nNodes) return;
    const int nu = __builtin_amdgcn_readfirstlane(wave);
    int idx[NB_K];
    #pragma unroll
    for (int k = 0; k < NB_K; ++k)
        idx[k] = __builtin_amdgcn_readfirstlane(nbrs[nu * NB_K + k]);
    float s[NB_K];
    #pragma unroll
    for (int k = 0; k < NB_K; ++k) s[k] = scores[idx[k]];
    float mx = s[0];
    #pragma unroll
    for (int k = 1; k < NB_K; ++k) mx = fmaxf(mx, s[k]);
    float sum = 0.f;
    #pragma unroll
    for (int k = 0; k < NB_K; ++k) { s[k] = __expf(s[k] - mx); sum += s[k]; }
    const float inv = 1.0f / sum;
    const float2* e2 = (const float2*)e;
    const size_t base2 = (size_t)nu * (NODES_H / 2) + lane;
    float2 self = e2[base2];
    float2 g[NB_K];
    #pragma unroll
    for (int k = 0; k < NB_K; ++k)
        g[k] = e2[(size_t)idx[k] * (NODES_H / 2) + lane];
    float o0 = self.x, o1 = self.y;
    #pragma unroll
    for (int k = 0; k < NB_K; ++k) {
        const float w = s[k] * inv;
        o0 = fmaf(w, g[k].x, o0);
        o1 = fmaf(w, g[k].y, o1);
    }
    ((float2*)out)[base2] = make_float2(o0, o1);
}

// ---------------------------------------------------------------------------
extern "C" void kernel_launch(void* const* d_in, const int* in_sizes, int n_in,
                              void* d_out, int out_size, void* d_ws, size_t ws_size,
                              hipStream_t stream) {
    const float* e   = (const float*)d_in[0];
    const float* Wa  = (const float*)d_in[1];
    const float* Wb  = (const float*)d_in[2];
    const float* ua  = (const float*)d_in[3];
    const int*   nb  = (const int*)d_in[4];
    float* out = (float*)d_out;

    const int nNodes = in_sizes[0] / NODES_H;   // 100000
    float* scores = (float*)d_ws;

    const size_t need = (size_t)WS_E16_OFF + (size_t)nNodes * NODES_H * 2;
    if (ws_size >= need) {
        void* wsB = (void*)((char*)d_ws + WS_B_OFF);
        unsigned short* e16 = (unsigned short*)((char*)d_ws + WS_E16_OFF);

        pack_kernel<<<8, 256, 0, stream>>>(Wa, wsB);

        const int nGroups = (nNodes + 15) / 16;            // 6250
        const int blocks1 = (nGroups + 7) / 8;             // 782 (8 waves/blk)
        score_kernel<<<blocks1, 512, 0, stream>>>(e, wsB, Wb, ua, scores, e16, nNodes);

        const int blocks2 = (nNodes + 3) / 4;              // one wave per node
        agg_kernel_h3<<<blocks2, 256, 0, stream>>>(e16, nb, scores, out, nNodes);
    } else {
        const int nGroups = (nNodes + 15) / 16;
        const int blocks1 = (nGroups + 3) / 4;
        score_self_kernel<<<blocks1, 256, 0, stream>>>(e, Wa, Wb, ua, scores, nNodes);
        const int blocks2 = (nNodes + 3) / 4;
        agg_kernel_f32<<<blocks2, 256, 0, stream>>>(e, nb, scores, out, nNodes);
    }
}